// Round 11
// baseline (290.865 us; speedup 1.0000x reference)
//
#include <hip/hip_runtime.h>

#define N_NODES 50000

typedef __attribute__((ext_vector_type(8))) short bf16x8;
typedef __attribute__((ext_vector_type(4))) float f32x4;

__device__ __forceinline__ ushort f2bf(float f) {
    union { float f; unsigned u; } v; v.f = f;
    unsigned r = v.u + 0x7fff + ((v.u >> 16) & 1);   // round-to-nearest-even
    return (ushort)(r >> 16);
}
__device__ __forceinline__ float bf2f(ushort u) {
    union { unsigned u; float f; } v; v.u = ((unsigned)u) << 16;
    return v.f;
}
__device__ __forceinline__ float bf2f_lo(unsigned u) {
    union { unsigned u; float f; } v; v.u = u << 16;
    return v.f;
}
__device__ __forceinline__ float bf2f_hi(unsigned u) {
    union { unsigned u; float f; } v; v.u = u & 0xffff0000u;
    return v.f;
}

__device__ __forceinline__ int eload(const void* ei, int idx, int is64) {
    return is64 ? (int)((const long long*)ei)[idx] : ((const int*)ei)[idx];
}

// ---------------- init: detect index width (block 0) + zero deg ----------
__global__ void k_init(const void* ei, int* flag, int* deg, int n) {
    if (blockIdx.x == 0) {
        __shared__ int bad;
        if (threadIdx.x == 0) bad = 0;
        __syncthreads();
        long long v = ((const long long*)ei)[threadIdx.x];
        if (v < 0 || v >= N_NODES) atomicOr(&bad, 1);
        __syncthreads();
        if (threadIdx.x == 0) *flag = bad ? 0 : 1;
    }
    int i = blockIdx.x * 256 + threadIdx.x;
    if (i < n) deg[i] = 0;
}

// ---------------- CSR build ----------------
__global__ void k_hist(const void* ei, const int* flag, int* deg, int e) {
    int base = (blockIdx.x * blockDim.x + threadIdx.x) * 4;
    if (base >= e) return;
    int is64 = *flag;
    if (base + 4 <= e) {
        int d0 = eload(ei, e + base,     is64);
        int d1 = eload(ei, e + base + 1, is64);
        int d2 = eload(ei, e + base + 2, is64);
        int d3 = eload(ei, e + base + 3, is64);
        atomicAdd(&deg[d0], 1);
        atomicAdd(&deg[d1], 1);
        atomicAdd(&deg[d2], 1);
        atomicAdd(&deg[d3], 1);
    } else {
        for (int i = base; i < e; ++i)
            atomicAdd(&deg[eload(ei, e + i, is64)], 1);
    }
}

// per-block (512) inclusive scan of deg -> rowptr+1 (local); raw block totals
__global__ __launch_bounds__(512)
void k_scanA(const int* __restrict__ deg, int* __restrict__ rp1,
             int* __restrict__ bsum, int n) {
    __shared__ int wsum[8];
    const int i = blockIdx.x * 512 + threadIdx.x;
    const int lane = threadIdx.x & 63, wid = threadIdx.x >> 6;
    int x = (i < n) ? deg[i] : 0;
    #pragma unroll
    for (int off = 1; off < 64; off <<= 1) {
        int y = __shfl_up(x, off, 64);
        if (lane >= off) x += y;
    }
    if (lane == 63) wsum[wid] = x;
    __syncthreads();
    if (wid == 0 && lane < 8) {
        int s = wsum[lane];
        #pragma unroll
        for (int off = 1; off < 8; off <<= 1) {
            int y = __shfl_up(s, off, 64);
            if (lane >= off) s += y;
        }
        wsum[lane] = s;
    }
    __syncthreads();
    int incl = x + (wid > 0 ? wsum[wid - 1] : 0);
    if (i < n) rp1[i] = incl;
    if (threadIdx.x == 0) bsum[blockIdx.x] = wsum[7];
}

// add block offsets (reduces bsum[<bx] in-block); emit rowptr, cur, dinv
__global__ __launch_bounds__(512)
void k_scanC(const int* __restrict__ deg, int* __restrict__ rowptr,
             const int* __restrict__ bsum, int* __restrict__ cur,
             float* __restrict__ dinv, int n, int nb) {
    __shared__ int spart[2];
    if (threadIdx.x < 128) {
        int v = (threadIdx.x < nb && (int)threadIdx.x < (int)blockIdx.x)
                ? bsum[threadIdx.x] : 0;
        #pragma unroll
        for (int o = 32; o; o >>= 1) v += __shfl_down(v, o, 64);
        if ((threadIdx.x & 63) == 0) spart[threadIdx.x >> 6] = v;
    }
    __syncthreads();
    const int off = spart[0] + spart[1];
    const int i = blockIdx.x * 512 + threadIdx.x;
    if (i >= n) return;
    const int d = deg[i];
    const int incl = rowptr[i + 1] + off;
    rowptr[i + 1] = incl;
    cur[i] = incl - d;
    dinv[i] = rsqrtf((float)(d + 1));   // +1 self-loop
    if (i == 0) rowptr[0] = 0;
}

// counting-sort scatter, XCD-phase partitioned by dst range
__global__ void k_fill(const void* ei, const int* flag, int* cur, int* adj, int e) {
    const int phase = blockIdx.x & 7;
    const int lo = phase * (N_NODES / 8);
    const int hi = lo + (N_NODES / 8);
    const int i = (blockIdx.x >> 3) * 256 + threadIdx.x;
    if (i >= e) return;
    const int is64 = *flag;
    const int d = eload(ei, e + i, is64);
    if (d >= lo && d < hi) {
        const int s = eload(ei, i, is64);
        adj[atomicAdd(&cur[d], 1)] = s;
    }
}

// ---------------- both weight splits in one kernel -----------------------
__global__ void k_splitW(const float* __restrict__ W1, const float* __restrict__ W2,
                         ushort* __restrict__ o1h, ushort* __restrict__ o1l,
                         ushort* __restrict__ o2h, ushort* __restrict__ o2l) {
    int idx = blockIdx.x * 256 + threadIdx.x;
    if (idx < 512 * 128) {                 // W1: K=128, N=512 (Bt1[n][k])
        int nn = idx >> 7, k = idx & 127;
        float v = W1[(size_t)k * 512 + nn];
        ushort hi = f2bf(v);
        o1h[idx] = hi;
        o1l[idx] = f2bf(v - bf2f(hi));
    } else {                               // W2: K=512, N=250->256 (Bt2[n][k])
        idx -= 512 * 128;
        int nn = idx >> 9, k = idx & 511;
        float v = (nn < 250) ? W2[(size_t)k * 250 + nn] : 0.0f;
        ushort hi = f2bf(v);
        o2h[idx] = hi;
        o2l[idx] = f2bf(v - bf2f(hi));
    }
}

// ---------------- pre-scale: xs[i][f] = bf16(dinv[i] * x[i][f]) ----------
__global__ __launch_bounds__(256)
void k_scale(const float* __restrict__ x, const float* __restrict__ dinv,
             ushort* __restrict__ xs, int n) {
    int idx = blockIdx.x * 256 + threadIdx.x;      // over n*64 u32 slots
    if (idx >= n * 64) return;
    int i = idx >> 6;
    float2 v = ((const float2*)x)[idx];
    float d = dinv[i];
    ((unsigned*)xs)[idx] = (unsigned)f2bf(d * v.x) | ((unsigned)f2bf(d * v.y) << 16);
}

// ---------------- pull layer 1 (F=128, xs bf16) -> bf16, 2 rows/wave -----
__global__ __launch_bounds__(256)
void k_pull128b(const int* __restrict__ rowptr, const int* __restrict__ adj,
                const float* __restrict__ dinv, const ushort* __restrict__ xs,
                ushort* __restrict__ ohi, int n) {
    const int iA = blockIdx.x * 8 + (threadIdx.x >> 6) * 2;
    const int iB = iA + 1;
    if (iA >= n) return;
    const int lane = threadIdx.x & 63;
    const unsigned* xs32 = (const unsigned*)xs;

    unsigned uA = xs32[(size_t)iA * 64 + lane];
    unsigned uB = xs32[(size_t)iB * 64 + lane];
    float a0 = bf2f_lo(uA), a1 = bf2f_hi(uA);
    float b0 = bf2f_lo(uB), b1 = bf2f_hi(uB);

    int jA = rowptr[iA];
    const int endA = rowptr[iA + 1];
    int jB = rowptr[iB];
    const int endB = rowptr[iB + 1];

    // joint loop: 4 edges of each row -> 8 independent gathers in flight
    while (jA + 4 <= endA && jB + 4 <= endB) {
        int sa0 = adj[jA], sa1 = adj[jA + 1], sa2 = adj[jA + 2], sa3 = adj[jA + 3];
        int sb0 = adj[jB], sb1 = adj[jB + 1], sb2 = adj[jB + 2], sb3 = adj[jB + 3];
        unsigned ua0 = xs32[(size_t)sa0 * 64 + lane];
        unsigned ua1 = xs32[(size_t)sa1 * 64 + lane];
        unsigned ua2 = xs32[(size_t)sa2 * 64 + lane];
        unsigned ua3 = xs32[(size_t)sa3 * 64 + lane];
        unsigned ub0 = xs32[(size_t)sb0 * 64 + lane];
        unsigned ub1 = xs32[(size_t)sb1 * 64 + lane];
        unsigned ub2 = xs32[(size_t)sb2 * 64 + lane];
        unsigned ub3 = xs32[(size_t)sb3 * 64 + lane];
        a0 += bf2f_lo(ua0) + bf2f_lo(ua1) + bf2f_lo(ua2) + bf2f_lo(ua3);
        a1 += bf2f_hi(ua0) + bf2f_hi(ua1) + bf2f_hi(ua2) + bf2f_hi(ua3);
        b0 += bf2f_lo(ub0) + bf2f_lo(ub1) + bf2f_lo(ub2) + bf2f_lo(ub3);
        b1 += bf2f_hi(ub0) + bf2f_hi(ub1) + bf2f_hi(ub2) + bf2f_hi(ub3);
        jA += 4; jB += 4;
    }
    // drain A
    for (; jA + 4 <= endA; jA += 4) {
        int s0 = adj[jA], s1 = adj[jA + 1], s2 = adj[jA + 2], s3 = adj[jA + 3];
        unsigned u0 = xs32[(size_t)s0 * 64 + lane];
        unsigned u1 = xs32[(size_t)s1 * 64 + lane];
        unsigned u2 = xs32[(size_t)s2 * 64 + lane];
        unsigned u3 = xs32[(size_t)s3 * 64 + lane];
        a0 += bf2f_lo(u0) + bf2f_lo(u1) + bf2f_lo(u2) + bf2f_lo(u3);
        a1 += bf2f_hi(u0) + bf2f_hi(u1) + bf2f_hi(u2) + bf2f_hi(u3);
    }
    for (; jA < endA; ++jA) {
        unsigned us = xs32[(size_t)adj[jA] * 64 + lane];
        a0 += bf2f_lo(us); a1 += bf2f_hi(us);
    }
    // drain B
    for (; jB + 4 <= endB; jB += 4) {
        int s0 = adj[jB], s1 = adj[jB + 1], s2 = adj[jB + 2], s3 = adj[jB + 3];
        unsigned u0 = xs32[(size_t)s0 * 64 + lane];
        unsigned u1 = xs32[(size_t)s1 * 64 + lane];
        unsigned u2 = xs32[(size_t)s2 * 64 + lane];
        unsigned u3 = xs32[(size_t)s3 * 64 + lane];
        b0 += bf2f_lo(u0) + bf2f_lo(u1) + bf2f_lo(u2) + bf2f_lo(u3);
        b1 += bf2f_hi(u0) + bf2f_hi(u1) + bf2f_hi(u2) + bf2f_hi(u3);
    }
    for (; jB < endB; ++jB) {
        unsigned us = xs32[(size_t)adj[jB] * 64 + lane];
        b0 += bf2f_lo(us); b1 += bf2f_hi(us);
    }

    const float dA = dinv[iA], dB = dinv[iB];
    a0 *= dA; a1 *= dA; b0 *= dB; b1 *= dB;
    ((unsigned*)ohi)[(size_t)iA * 64 + lane] =
        (unsigned)f2bf(a0) | ((unsigned)f2bf(a1) << 16);
    ((unsigned*)ohi)[(size_t)iB * 64 + lane] =
        (unsigned)f2bf(b0) | ((unsigned)f2bf(b1) << 16);
}

// ---------------- pull layer 2 (F=250, t bf16 ld=256), 2 rows/wave -------
__device__ __forceinline__ void p250_store(float* __restrict__ out,
                                           const float* __restrict__ bias,
                                           int i, int lane, float d,
                                           float a0, float a1, float a2, float a3) {
    const int c0 = lane * 4;
    if (lane < 62) {
        float2 b0 = *(const float2*)&bias[c0];
        float2 b1 = *(const float2*)&bias[c0 + 2];
        float2 o0, o1;
        o0.x = fmaxf(d * a0 + b0.x, 0.0f);
        o0.y = fmaxf(d * a1 + b0.y, 0.0f);
        o1.x = fmaxf(d * a2 + b1.x, 0.0f);
        o1.y = fmaxf(d * a3 + b1.y, 0.0f);
        *(float2*)&out[(size_t)i * 250 + c0] = o0;
        *(float2*)&out[(size_t)i * 250 + c0 + 2] = o1;
    } else if (lane == 62) {   // cols 248,249
        float2 b0 = *(const float2*)&bias[248];
        float2 o0;
        o0.x = fmaxf(d * a0 + b0.x, 0.0f);
        o0.y = fmaxf(d * a1 + b0.y, 0.0f);
        *(float2*)&out[(size_t)i * 250 + 248] = o0;
    }
}

__global__ __launch_bounds__(256)
void k_pull250w(const int* __restrict__ rowptr, const int* __restrict__ adj,
                const float* __restrict__ dinv, const ushort* __restrict__ t,
                const float* __restrict__ bias, float* __restrict__ out, int n) {
    const int iA = blockIdx.x * 8 + (threadIdx.x >> 6) * 2;
    const int iB = iA + 1;
    if (iA >= n) return;
    const int lane = threadIdx.x & 63;
    const uint2* t2 = (const uint2*)t;   // [row][64] x uint2 (256 bf16)

    uint2 uA = t2[(size_t)iA * 64 + lane];
    uint2 uB = t2[(size_t)iB * 64 + lane];
    float a0 = bf2f_lo(uA.x), a1 = bf2f_hi(uA.x);
    float a2 = bf2f_lo(uA.y), a3 = bf2f_hi(uA.y);
    float b0 = bf2f_lo(uB.x), b1 = bf2f_hi(uB.x);
    float b2 = bf2f_lo(uB.y), b3 = bf2f_hi(uB.y);

    int jA = rowptr[iA];
    const int endA = rowptr[iA + 1];
    int jB = rowptr[iB];
    const int endB = rowptr[iB + 1];

    // joint loop: 4 gathers per row, 8 independent 8-B loads in flight
    while (jA + 4 <= endA && jB + 4 <= endB) {
        int sa0 = adj[jA], sa1 = adj[jA + 1], sa2 = adj[jA + 2], sa3 = adj[jA + 3];
        int sb0 = adj[jB], sb1 = adj[jB + 1], sb2 = adj[jB + 2], sb3 = adj[jB + 3];
        uint2 ua0 = t2[(size_t)sa0 * 64 + lane];
        uint2 ua1 = t2[(size_t)sa1 * 64 + lane];
        uint2 ua2 = t2[(size_t)sa2 * 64 + lane];
        uint2 ua3 = t2[(size_t)sa3 * 64 + lane];
        uint2 ub0 = t2[(size_t)sb0 * 64 + lane];
        uint2 ub1 = t2[(size_t)sb1 * 64 + lane];
        uint2 ub2 = t2[(size_t)sb2 * 64 + lane];
        uint2 ub3 = t2[(size_t)sb3 * 64 + lane];
        a0 += bf2f_lo(ua0.x) + bf2f_lo(ua1.x) + bf2f_lo(ua2.x) + bf2f_lo(ua3.x);
        a1 += bf2f_hi(ua0.x) + bf2f_hi(ua1.x) + bf2f_hi(ua2.x) + bf2f_hi(ua3.x);
        a2 += bf2f_lo(ua0.y) + bf2f_lo(ua1.y) + bf2f_lo(ua2.y) + bf2f_lo(ua3.y);
        a3 += bf2f_hi(ua0.y) + bf2f_hi(ua1.y) + bf2f_hi(ua2.y) + bf2f_hi(ua3.y);
        b0 += bf2f_lo(ub0.x) + bf2f_lo(ub1.x) + bf2f_lo(ub2.x) + bf2f_lo(ub3.x);
        b1 += bf2f_hi(ub0.x) + bf2f_hi(ub1.x) + bf2f_hi(ub2.x) + bf2f_hi(ub3.x);
        b2 += bf2f_lo(ub0.y) + bf2f_lo(ub1.y) + bf2f_lo(ub2.y) + bf2f_lo(ub3.y);
        b3 += bf2f_hi(ub0.y) + bf2f_hi(ub1.y) + bf2f_hi(ub2.y) + bf2f_hi(ub3.y);
        jA += 4; jB += 4;
    }
    // drain A
    for (; jA + 4 <= endA; jA += 4) {
        int s0 = adj[jA], s1 = adj[jA + 1], s2 = adj[jA + 2], s3 = adj[jA + 3];
        uint2 u0 = t2[(size_t)s0 * 64 + lane];
        uint2 u1 = t2[(size_t)s1 * 64 + lane];
        uint2 u2 = t2[(size_t)s2 * 64 + lane];
        uint2 u3 = t2[(size_t)s3 * 64 + lane];
        a0 += bf2f_lo(u0.x) + bf2f_lo(u1.x) + bf2f_lo(u2.x) + bf2f_lo(u3.x);
        a1 += bf2f_hi(u0.x) + bf2f_hi(u1.x) + bf2f_hi(u2.x) + bf2f_hi(u3.x);
        a2 += bf2f_lo(u0.y) + bf2f_lo(u1.y) + bf2f_lo(u2.y) + bf2f_lo(u3.y);
        a3 += bf2f_hi(u0.y) + bf2f_hi(u1.y) + bf2f_hi(u2.y) + bf2f_hi(u3.y);
    }
    for (; jA < endA; ++jA) {
        uint2 us = t2[(size_t)adj[jA] * 64 + lane];
        a0 += bf2f_lo(us.x); a1 += bf2f_hi(us.x);
        a2 += bf2f_lo(us.y); a3 += bf2f_hi(us.y);
    }
    // drain B
    for (; jB + 4 <= endB; jB += 4) {
        int s0 = adj[jB], s1 = adj[jB + 1], s2 = adj[jB + 2], s3 = adj[jB + 3];
        uint2 u0 = t2[(size_t)s0 * 64 + lane];
        uint2 u1 = t2[(size_t)s1 * 64 + lane];
        uint2 u2 = t2[(size_t)s2 * 64 + lane];
        uint2 u3 = t2[(size_t)s3 * 64 + lane];
        b0 += bf2f_lo(u0.x) + bf2f_lo(u1.x) + bf2f_lo(u2.x) + bf2f_lo(u3.x);
        b1 += bf2f_hi(u0.x) + bf2f_hi(u1.x) + bf2f_hi(u2.x) + bf2f_hi(u3.x);
        b2 += bf2f_lo(u0.y) + bf2f_lo(u1.y) + bf2f_lo(u2.y) + bf2f_lo(u3.y);
        b3 += bf2f_hi(u0.y) + bf2f_hi(u1.y) + bf2f_hi(u2.y) + bf2f_hi(u3.y);
    }
    for (; jB < endB; ++jB) {
        uint2 us = t2[(size_t)adj[jB] * 64 + lane];
        b0 += bf2f_lo(us.x); b1 += bf2f_hi(us.x);
        b2 += bf2f_lo(us.y); b3 += bf2f_hi(us.y);
    }

    p250_store(out, bias, iA, lane, dinv[iA], a0, a1, a2, a3);
    p250_store(out, bias, iB, lane, dinv[iB], b0, b1, b2, b3);
}

// ---------------- bf16 MFMA GEMM: C = A[MxK] @ Bt[N][K]^T ----------------
__device__ __forceinline__ void gl16(const ushort* g, ushort* l) {
    __builtin_amdgcn_global_load_lds((const __attribute__((address_space(1))) void*)g,
                                     (__attribute__((address_space(3))) void*)l,
                                     16, 0, 0);
}

#define OFF_BH 4096        // 4 chunks * 1024 (A)
#define OFF_BL 12288       // OFF_BH + 4*2048
#define SMEM_HALF 20480    // OFF_BL + 4*2048  (= 40960 B; x2 = 80 KiB)

__global__ __launch_bounds__(256, 2)
void k_mfma(const ushort* __restrict__ A, const ushort* __restrict__ Bhi,
            const ushort* __restrict__ Blo, const float* __restrict__ bias,
            const float* __restrict__ rscale, ushort* __restrict__ outp,
            int M, int K, int ldc, int mode, int CX, int PY) {
    __shared__ __align__(16) ushort smem[2 * SMEM_HALF];

    // XCD swizzle: a panel's CX col-blocks get ids ≡ same (mod 8)
    int id = blockIdx.x;
    const int gsz = CX * 8;
    const int nfull = (PY >> 3) * gsz;
    int bx, by;
    if (id < nfull) {
        int gg = id / gsz;
        int r  = id - gg * gsz;
        bx = r >> 3;
        by = gg * 8 + (r & 7);
    } else {
        int rem  = id - nfull;
        int pbase = (PY >> 3) << 3;
        int prem  = PY - pbase;
        by = pbase + rem % prem;
        bx = rem / prem;
    }
    const int brow = by * 128;
    const int bcol = bx * 256;

    const int tid  = threadIdx.x;
    const int lane = tid & 63;
    const int w    = tid >> 6;
    const int g    = lane >> 4;
    const int lr   = lane & 15;

    auto STAGE = [&](ushort* buf, int k0) {
        const int kofs = k0 + w * 8;
        #pragma unroll
        for (int t2 = 0; t2 < 2; ++t2)
            gl16(A + (size_t)(brow + t2 * 64 + lane) * K + kofs,
                 buf + w * 1024 + t2 * 512);
        #pragma unroll
        for (int t4 = 0; t4 < 4; ++t4)
            gl16(Bhi + (size_t)(bcol + t4 * 64 + lane) * K + kofs,
                 buf + OFF_BH + w * 2048 + t4 * 512);
        #pragma unroll
        for (int t4 = 0; t4 < 4; ++t4)
            gl16(Blo + (size_t)(bcol + t4 * 64 + lane) * K + kofs,
                 buf + OFF_BL + w * 2048 + t4 * 512);
    };

    f32x4 acc[8][4] = {};

    auto COMPUTE = [&](const ushort* rb) {
        bf16x8 af[8], bh[4], bl[4];
        #pragma unroll
        for (int nt = 0; nt < 4; ++nt) {
            const int bo = g * 2048 + (w * 64 + nt * 16 + lr) * 8;
            bh[nt] = *(const bf16x8*)(rb + OFF_BH + bo);
            bl[nt] = *(const bf16x8*)(rb + OFF_BL + bo);
        }
        #pragma unroll
        for (int mt = 0; mt < 8; ++mt)
            af[mt] = *(const bf16x8*)(rb + g * 1024 + (mt * 16 + lr) * 8);
        #pragma unroll
        for (int mt = 0; mt < 8; ++mt)
            #pragma unroll
            for (int nt = 0; nt < 4; ++nt) {
                acc[mt][nt] = __builtin_amdgcn_mfma_f32_16x16x32_bf16(bh[nt], af[mt], acc[mt][nt], 0, 0, 0);
                acc[mt][nt] = __builtin_amdgcn_mfma_f32_16x16x32_bf16(bl[nt], af[mt], acc[mt][nt], 0, 0, 0);
            }
    };

    STAGE(smem, 0);
    int cur = 0;
    for (int k0 = 32; k0 < K; k0 += 32) {
        STAGE(smem + (cur ^ 1) * SMEM_HALF, k0);
        asm volatile("s_waitcnt vmcnt(10)" ::: "memory");
        __builtin_amdgcn_sched_barrier(0);
        __builtin_amdgcn_s_barrier();
        COMPUTE(smem + cur * SMEM_HALF);
        __builtin_amdgcn_sched_barrier(0);
        __builtin_amdgcn_s_barrier();
        cur ^= 1;
    }
    asm volatile("s_waitcnt vmcnt(0)" ::: "memory");
    __builtin_amdgcn_sched_barrier(0);
    __builtin_amdgcn_s_barrier();
    COMPUTE(smem + cur * SMEM_HALF);

    #pragma unroll
    for (int mt = 0; mt < 8; ++mt) {
        const int gr = brow + mt * 16 + lr;
        if (gr >= M) continue;
        const float rs = (mode == 0) ? rscale[gr] : 0.0f;
        #pragma unroll
        for (int nt = 0; nt < 4; ++nt) {
            const int gc0 = bcol + w * 64 + nt * 16 + g * 4;
            float v0, v1, v2, v3;
            if (mode == 0) {
                v0 = acc[mt][nt][0] * rs; v1 = acc[mt][nt][1] * rs;
                v2 = acc[mt][nt][2] * rs; v3 = acc[mt][nt][3] * rs;
            } else {
                const float4 bv = *(const float4*)&bias[gc0];
                v0 = fmaxf(acc[mt][nt][0] + bv.x, 0.0f);
                v1 = fmaxf(acc[mt][nt][1] + bv.y, 0.0f);
                v2 = fmaxf(acc[mt][nt][2] + bv.z, 0.0f);
                v3 = fmaxf(acc[mt][nt][3] + bv.w, 0.0f);
            }
            uint2 pk;
            pk.x = (unsigned)f2bf(v0) | ((unsigned)f2bf(v1) << 16);
            pk.y = (unsigned)f2bf(v2) | ((unsigned)f2bf(v3) << 16);
            *(uint2*)(outp + (size_t)gr * ldc + gc0) = pk;
        }
    }
}

extern "C" void kernel_launch(void* const* d_in, const int* in_sizes, int n_in,
                              void* d_out, int out_size, void* d_ws, size_t ws_size,
                              hipStream_t stream) {
    const float* x  = (const float*)d_in[0];
    const void*  ei = d_in[1];
    const float* W1 = (const float*)d_in[2];
    const float* b1 = (const float*)d_in[3];
    const float* W2 = (const float*)d_in[4];
    const float* b2 = (const float*)d_in[5];
    float* out = (float*)d_out;

    const int N = N_NODES;
    const int E = in_sizes[1] / 2;
    const int MPAD = 50048;             // 391 * 128
    const int NSCB = (N + 511) / 512;   // 98 scan blocks

    // ---- workspace layout ----
    char* base = (char*)d_ws;
    int*   flag   = (int*)base;                        // 256 B slot
    int*   deg    = (int*)(base + 256);                // [51200]
    int*   rowptr = deg + 51200;
    int*   cur    = rowptr + 51200;
    float* dinv   = (float*)(cur + 51200);
    int*   bsum   = (int*)(dinv + 51200);              // [128]
    int*   adj    = bsum + 128;                        // [E]
    char*  p      = (char*)(adj + ((E + 63) & ~63));
    ushort* A1hi  = (ushort*)p;  p += (size_t)MPAD * 128 * 2;
    ushort* A1xx  = (ushort*)p;  p += (size_t)MPAD * 128 * 2;  // pad (tbuf tail)
    ushort* tbuf  = A1hi;        // [N][256] bf16, aliases A1hi+pad (dead after GEMM1)
    ushort* h1hi  = (ushort*)p;  p += (size_t)MPAD * 512 * 2;  // plain bf16
    ushort* Bt1hi = (ushort*)p;  p += 512 * 128 * 2;
    ushort* Bt1lo = (ushort*)p;  p += 512 * 128 * 2;
    ushort* Bt2hi = (ushort*)p;  p += 256 * 512 * 2;
    ushort* Bt2lo = (ushort*)p;  p += 256 * 512 * 2;
    ushort* xs    = (ushort*)p;  p += (size_t)MPAD * 128 * 2;  // bf16 dinv*x
    (void)A1xx;

    // 1. CSR build + normalization
    k_init<<<(N + 255) / 256, 256, 0, stream>>>(ei, flag, deg, N);
    k_hist<<<(E / 4 + 255) / 256, 256, 0, stream>>>(ei, flag, deg, E);
    k_scanA<<<NSCB, 512, 0, stream>>>(deg, rowptr + 1, bsum, N);
    k_scanC<<<NSCB, 512, 0, stream>>>(deg, rowptr, bsum, cur, dinv, N, NSCB);
    k_fill<<<((E + 255) / 256) * 8, 256, 0, stream>>>(ei, flag, cur, adj, E);

    // 2. weight prep (both) + pre-scaled features
    k_splitW<<<(512 * 128 + 256 * 512) / 256, 256, 0, stream>>>(
        W1, W2, Bt1hi, Bt1lo, Bt2hi, Bt2lo);
    k_scale<<<(N * 64 + 255) / 256, 256, 0, stream>>>(x, dinv, xs, N);

    // 3. layer-1 aggregation -> A1 (bf16)  [N,128]   (8 rows/block)
    k_pull128b<<<(N + 7) / 8, 256, 0, stream>>>(rowptr, adj, dinv, xs, A1hi, N);

    // 4. h1 = relu(A1 @ W1 + b1) -> bf16 [N,512]   (2 col-blocks of 256)
    k_mfma<<<2 * 391, 256, 0, stream>>>(A1hi, Bt1hi, Bt1lo, b1, nullptr, h1hi,
                                        N, 128, 512, 1, 2, 391);

    // 5. t = bf16( dinv[row] * (h1 @ W2) )  [N,256]  (1 col-block of 256)
    k_mfma<<<1 * 391, 256, 0, stream>>>(h1hi, Bt2hi, Bt2lo, nullptr, dinv, tbuf,
                                        N, 512, 256, 0, 1, 391);

    // 6. layer-2 aggregation + bias + relu -> out  [N,250]  (8 rows/block)
    k_pull250w<<<(N + 7) / 8, 256, 0, stream>>>(rowptr, adj, dinv, tbuf, b2, out, N);
}

// Round 12
// 264.404 us; speedup vs baseline: 1.1001x; 1.1001x over previous
//
#include <hip/hip_runtime.h>

#define N_NODES 50000

typedef __attribute__((ext_vector_type(8))) short bf16x8;
typedef __attribute__((ext_vector_type(4))) float f32x4;

__device__ __forceinline__ ushort f2bf(float f) {
    union { float f; unsigned u; } v; v.f = f;
    unsigned r = v.u + 0x7fff + ((v.u >> 16) & 1);   // round-to-nearest-even
    return (ushort)(r >> 16);
}
__device__ __forceinline__ float bf2f(ushort u) {
    union { unsigned u; float f; } v; v.u = ((unsigned)u) << 16;
    return v.f;
}
__device__ __forceinline__ float bf2f_lo(unsigned u) {
    union { unsigned u; float f; } v; v.u = u << 16;
    return v.f;
}
__device__ __forceinline__ float bf2f_hi(unsigned u) {
    union { unsigned u; float f; } v; v.u = u & 0xffff0000u;
    return v.f;
}

__device__ __forceinline__ int eload(const void* ei, int idx, int is64) {
    return is64 ? (int)((const long long*)ei)[idx] : ((const int*)ei)[idx];
}

// ---------------- init: detect index width (block 0) + zero deg ----------
__global__ void k_init(const void* ei, int* flag, int* deg, int n) {
    if (blockIdx.x == 0) {
        __shared__ int bad;
        if (threadIdx.x == 0) bad = 0;
        __syncthreads();
        long long v = ((const long long*)ei)[threadIdx.x];
        if (v < 0 || v >= N_NODES) atomicOr(&bad, 1);
        __syncthreads();
        if (threadIdx.x == 0) *flag = bad ? 0 : 1;
    }
    int i = blockIdx.x * 256 + threadIdx.x;
    if (i < n) deg[i] = 0;
}

// ---------------- CSR build ----------------
__global__ void k_hist(const void* ei, const int* flag, int* deg, int e) {
    int base = (blockIdx.x * blockDim.x + threadIdx.x) * 4;
    if (base >= e) return;
    int is64 = *flag;
    if (base + 4 <= e) {
        int d0 = eload(ei, e + base,     is64);
        int d1 = eload(ei, e + base + 1, is64);
        int d2 = eload(ei, e + base + 2, is64);
        int d3 = eload(ei, e + base + 3, is64);
        atomicAdd(&deg[d0], 1);
        atomicAdd(&deg[d1], 1);
        atomicAdd(&deg[d2], 1);
        atomicAdd(&deg[d3], 1);
    } else {
        for (int i = base; i < e; ++i)
            atomicAdd(&deg[eload(ei, e + i, is64)], 1);
    }
}

// per-block (512) inclusive scan of deg -> rowptr+1 (local); raw block totals
__global__ __launch_bounds__(512)
void k_scanA(const int* __restrict__ deg, int* __restrict__ rp1,
             int* __restrict__ bsum, int n) {
    __shared__ int wsum[8];
    const int i = blockIdx.x * 512 + threadIdx.x;
    const int lane = threadIdx.x & 63, wid = threadIdx.x >> 6;
    int x = (i < n) ? deg[i] : 0;
    #pragma unroll
    for (int off = 1; off < 64; off <<= 1) {
        int y = __shfl_up(x, off, 64);
        if (lane >= off) x += y;
    }
    if (lane == 63) wsum[wid] = x;
    __syncthreads();
    if (wid == 0 && lane < 8) {
        int s = wsum[lane];
        #pragma unroll
        for (int off = 1; off < 8; off <<= 1) {
            int y = __shfl_up(s, off, 64);
            if (lane >= off) s += y;
        }
        wsum[lane] = s;
    }
    __syncthreads();
    int incl = x + (wid > 0 ? wsum[wid - 1] : 0);
    if (i < n) rp1[i] = incl;
    if (threadIdx.x == 0) bsum[blockIdx.x] = wsum[7];
}

// add block offsets (reduces bsum[<bx] in-block); emit rowptr, cur, dinv
__global__ __launch_bounds__(512)
void k_scanC(const int* __restrict__ deg, int* __restrict__ rowptr,
             const int* __restrict__ bsum, int* __restrict__ cur,
             float* __restrict__ dinv, int n, int nb) {
    __shared__ int spart[2];
    if (threadIdx.x < 128) {
        int v = (threadIdx.x < nb && (int)threadIdx.x < (int)blockIdx.x)
                ? bsum[threadIdx.x] : 0;
        #pragma unroll
        for (int o = 32; o; o >>= 1) v += __shfl_down(v, o, 64);
        if ((threadIdx.x & 63) == 0) spart[threadIdx.x >> 6] = v;
    }
    __syncthreads();
    const int off = spart[0] + spart[1];
    const int i = blockIdx.x * 512 + threadIdx.x;
    if (i >= n) return;
    const int d = deg[i];
    const int incl = rowptr[i + 1] + off;
    rowptr[i + 1] = incl;
    cur[i] = incl - d;
    dinv[i] = rsqrtf((float)(d + 1));   // +1 self-loop
    if (i == 0) rowptr[0] = 0;
}

// counting-sort scatter, XCD-phase partitioned by dst range
__global__ void k_fill(const void* ei, const int* flag, int* cur, int* adj, int e) {
    const int phase = blockIdx.x & 7;
    const int lo = phase * (N_NODES / 8);
    const int hi = lo + (N_NODES / 8);
    const int i = (blockIdx.x >> 3) * 256 + threadIdx.x;
    if (i >= e) return;
    const int is64 = *flag;
    const int d = eload(ei, e + i, is64);
    if (d >= lo && d < hi) {
        const int s = eload(ei, i, is64);
        adj[atomicAdd(&cur[d], 1)] = s;
    }
}

// ---------------- weight transpose to bf16: Bt[n][k] = bf16(W[k][n]) -----
__global__ void k_splitW(const float* __restrict__ W1, const float* __restrict__ W2,
                         ushort* __restrict__ o1, ushort* __restrict__ o2) {
    int idx = blockIdx.x * 256 + threadIdx.x;
    if (idx < 512 * 128) {                 // W1: K=128, N=512 (Bt1[n][k])
        int nn = idx >> 7, k = idx & 127;
        o1[idx] = f2bf(W1[(size_t)k * 512 + nn]);
    } else {                               // W2: K=512, N=250->256 (Bt2[n][k])
        idx -= 512 * 128;
        int nn = idx >> 9, k = idx & 511;
        o2[idx] = (nn < 250) ? f2bf(W2[(size_t)k * 250 + nn]) : (ushort)0;
    }
}

// ---------------- pre-scale: xs[i][f] = bf16(dinv[i] * x[i][f]) ----------
__global__ __launch_bounds__(256)
void k_scale(const float* __restrict__ x, const float* __restrict__ dinv,
             ushort* __restrict__ xs, int n) {
    int idx = blockIdx.x * 256 + threadIdx.x;      // over n*64 u32 slots
    if (idx >= n * 64) return;
    int i = idx >> 6;
    float2 v = ((const float2*)x)[idx];
    float d = dinv[i];
    ((unsigned*)xs)[idx] = (unsigned)f2bf(d * v.x) | ((unsigned)f2bf(d * v.y) << 16);
}

// ---------------- pull layer 1 (F=128, xs bf16) -> bf16, 1 row/wave ------
__global__ __launch_bounds__(256)
void k_pull128b(const int* __restrict__ rowptr, const int* __restrict__ adj,
                const float* __restrict__ dinv, const ushort* __restrict__ xs,
                ushort* __restrict__ ohi, int n) {
    const int i = blockIdx.x * 4 + (threadIdx.x >> 6);
    if (i >= n) return;
    const int lane = threadIdx.x & 63;
    const unsigned* xs32 = (const unsigned*)xs;
    unsigned u = xs32[(size_t)i * 64 + lane];
    float a0 = bf2f_lo(u), a1 = bf2f_hi(u);
    int j = rowptr[i];
    const int end = rowptr[i + 1];
    for (; j + 8 <= end; j += 8) {
        int s0 = adj[j],     s1 = adj[j + 1], s2 = adj[j + 2], s3 = adj[j + 3];
        int s4 = adj[j + 4], s5 = adj[j + 5], s6 = adj[j + 6], s7 = adj[j + 7];
        unsigned u0 = xs32[(size_t)s0 * 64 + lane];
        unsigned u1 = xs32[(size_t)s1 * 64 + lane];
        unsigned u2 = xs32[(size_t)s2 * 64 + lane];
        unsigned u3 = xs32[(size_t)s3 * 64 + lane];
        unsigned u4 = xs32[(size_t)s4 * 64 + lane];
        unsigned u5 = xs32[(size_t)s5 * 64 + lane];
        unsigned u6 = xs32[(size_t)s6 * 64 + lane];
        unsigned u7 = xs32[(size_t)s7 * 64 + lane];
        a0 += bf2f_lo(u0) + bf2f_lo(u1) + bf2f_lo(u2) + bf2f_lo(u3);
        a1 += bf2f_hi(u0) + bf2f_hi(u1) + bf2f_hi(u2) + bf2f_hi(u3);
        a0 += bf2f_lo(u4) + bf2f_lo(u5) + bf2f_lo(u6) + bf2f_lo(u7);
        a1 += bf2f_hi(u4) + bf2f_hi(u5) + bf2f_hi(u6) + bf2f_hi(u7);
    }
    for (; j + 4 <= end; j += 4) {
        int s0 = adj[j], s1 = adj[j + 1], s2 = adj[j + 2], s3 = adj[j + 3];
        unsigned u0 = xs32[(size_t)s0 * 64 + lane];
        unsigned u1 = xs32[(size_t)s1 * 64 + lane];
        unsigned u2 = xs32[(size_t)s2 * 64 + lane];
        unsigned u3 = xs32[(size_t)s3 * 64 + lane];
        a0 += bf2f_lo(u0) + bf2f_lo(u1) + bf2f_lo(u2) + bf2f_lo(u3);
        a1 += bf2f_hi(u0) + bf2f_hi(u1) + bf2f_hi(u2) + bf2f_hi(u3);
    }
    for (; j < end; ++j) {
        unsigned us = xs32[(size_t)adj[j] * 64 + lane];
        a0 += bf2f_lo(us);
        a1 += bf2f_hi(us);
    }
    const float di = dinv[i];
    a0 *= di; a1 *= di;
    ((unsigned*)ohi)[(size_t)i * 64 + lane] =
        (unsigned)f2bf(a0) | ((unsigned)f2bf(a1) << 16);
}

// ---------------- pull layer 2 (F=250, t bf16 ld=256), 1 row/wave --------
__global__ __launch_bounds__(256)
void k_pull250v(const int* __restrict__ rowptr, const int* __restrict__ adj,
                const float* __restrict__ dinv, const ushort* __restrict__ t,
                const float* __restrict__ bias, float* __restrict__ out, int n) {
    const int i = blockIdx.x * 4 + (threadIdx.x >> 6);
    if (i >= n) return;
    const int lane = threadIdx.x & 63;
    const uint2* t2 = (const uint2*)t;   // [row][64] x uint2 (256 bf16)
    uint2 u = t2[(size_t)i * 64 + lane];
    float a0 = bf2f_lo(u.x), a1 = bf2f_hi(u.x);
    float a2 = bf2f_lo(u.y), a3 = bf2f_hi(u.y);
    int j = rowptr[i];
    const int end = rowptr[i + 1];
    for (; j + 8 <= end; j += 8) {
        int s0 = adj[j],     s1 = adj[j + 1], s2 = adj[j + 2], s3 = adj[j + 3];
        int s4 = adj[j + 4], s5 = adj[j + 5], s6 = adj[j + 6], s7 = adj[j + 7];
        uint2 u0 = t2[(size_t)s0 * 64 + lane];
        uint2 u1 = t2[(size_t)s1 * 64 + lane];
        uint2 u2 = t2[(size_t)s2 * 64 + lane];
        uint2 u3 = t2[(size_t)s3 * 64 + lane];
        uint2 u4 = t2[(size_t)s4 * 64 + lane];
        uint2 u5 = t2[(size_t)s5 * 64 + lane];
        uint2 u6 = t2[(size_t)s6 * 64 + lane];
        uint2 u7 = t2[(size_t)s7 * 64 + lane];
        a0 += bf2f_lo(u0.x) + bf2f_lo(u1.x) + bf2f_lo(u2.x) + bf2f_lo(u3.x);
        a1 += bf2f_hi(u0.x) + bf2f_hi(u1.x) + bf2f_hi(u2.x) + bf2f_hi(u3.x);
        a2 += bf2f_lo(u0.y) + bf2f_lo(u1.y) + bf2f_lo(u2.y) + bf2f_lo(u3.y);
        a3 += bf2f_hi(u0.y) + bf2f_hi(u1.y) + bf2f_hi(u2.y) + bf2f_hi(u3.y);
        a0 += bf2f_lo(u4.x) + bf2f_lo(u5.x) + bf2f_lo(u6.x) + bf2f_lo(u7.x);
        a1 += bf2f_hi(u4.x) + bf2f_hi(u5.x) + bf2f_hi(u6.x) + bf2f_hi(u7.x);
        a2 += bf2f_lo(u4.y) + bf2f_lo(u5.y) + bf2f_lo(u6.y) + bf2f_lo(u7.y);
        a3 += bf2f_hi(u4.y) + bf2f_hi(u5.y) + bf2f_hi(u6.y) + bf2f_hi(u7.y);
    }
    for (; j + 4 <= end; j += 4) {
        int s0 = adj[j], s1 = adj[j + 1], s2 = adj[j + 2], s3 = adj[j + 3];
        uint2 u0 = t2[(size_t)s0 * 64 + lane];
        uint2 u1 = t2[(size_t)s1 * 64 + lane];
        uint2 u2 = t2[(size_t)s2 * 64 + lane];
        uint2 u3 = t2[(size_t)s3 * 64 + lane];
        a0 += bf2f_lo(u0.x) + bf2f_lo(u1.x) + bf2f_lo(u2.x) + bf2f_lo(u3.x);
        a1 += bf2f_hi(u0.x) + bf2f_hi(u1.x) + bf2f_hi(u2.x) + bf2f_hi(u3.x);
        a2 += bf2f_lo(u0.y) + bf2f_lo(u1.y) + bf2f_lo(u2.y) + bf2f_lo(u3.y);
        a3 += bf2f_hi(u0.y) + bf2f_hi(u1.y) + bf2f_hi(u2.y) + bf2f_hi(u3.y);
    }
    for (; j < end; ++j) {
        uint2 us = t2[(size_t)adj[j] * 64 + lane];
        a0 += bf2f_lo(us.x); a1 += bf2f_hi(us.x);
        a2 += bf2f_lo(us.y); a3 += bf2f_hi(us.y);
    }
    const float d = dinv[i];
    const int c0 = lane * 4;
    if (lane < 62) {
        float2 b0 = *(const float2*)&bias[c0];
        float2 b1 = *(const float2*)&bias[c0 + 2];
        float2 o0, o1;
        o0.x = fmaxf(d * a0 + b0.x, 0.0f);
        o0.y = fmaxf(d * a1 + b0.y, 0.0f);
        o1.x = fmaxf(d * a2 + b1.x, 0.0f);
        o1.y = fmaxf(d * a3 + b1.y, 0.0f);
        *(float2*)&out[(size_t)i * 250 + c0] = o0;
        *(float2*)&out[(size_t)i * 250 + c0 + 2] = o1;
    } else if (lane == 62) {   // cols 248,249
        float2 b0 = *(const float2*)&bias[248];
        float2 o0;
        o0.x = fmaxf(d * a0 + b0.x, 0.0f);
        o0.y = fmaxf(d * a1 + b0.y, 0.0f);
        *(float2*)&out[(size_t)i * 250 + 248] = o0;
    }
}

// ---------------- bf16 MFMA GEMM: C = A[MxK] @ Bt[N][K]^T ----------------
// Plain bf16 A and B, 1 MFMA product. Tile 128 rows x 256 cols, BK=32,
// 4 waves; wave w owns 64-col strip and stages chunk c=w of both arrays.
// Counted vmcnt(6) double-buffer, LDS 48 KiB.
__device__ __forceinline__ void gl16(const ushort* g, ushort* l) {
    __builtin_amdgcn_global_load_lds((const __attribute__((address_space(1))) void*)g,
                                     (__attribute__((address_space(3))) void*)l,
                                     16, 0, 0);
}

#define OFF_B 4096         // 4 chunks * 1024 (A)
#define SMEM_HALF 12288    // OFF_B + 4*2048  (= 24576 B; x2 = 48 KiB)

__global__ __launch_bounds__(256, 2)
void k_mfma(const ushort* __restrict__ A, const ushort* __restrict__ B,
            const float* __restrict__ bias, const float* __restrict__ rscale,
            ushort* __restrict__ outp, int M, int K, int ldc, int mode,
            int CX, int PY) {
    __shared__ __align__(16) ushort smem[2 * SMEM_HALF];

    // XCD swizzle: a panel's CX col-blocks get ids ≡ same (mod 8)
    int id = blockIdx.x;
    const int gsz = CX * 8;
    const int nfull = (PY >> 3) * gsz;
    int bx, by;
    if (id < nfull) {
        int gg = id / gsz;
        int r  = id - gg * gsz;
        bx = r >> 3;
        by = gg * 8 + (r & 7);
    } else {
        int rem  = id - nfull;
        int pbase = (PY >> 3) << 3;
        int prem  = PY - pbase;
        by = pbase + rem % prem;
        bx = rem / prem;
    }
    const int brow = by * 128;
    const int bcol = bx * 256;

    const int tid  = threadIdx.x;
    const int lane = tid & 63;
    const int w    = tid >> 6;
    const int g    = lane >> 4;
    const int lr   = lane & 15;

    auto STAGE = [&](ushort* buf, int k0) {
        const int kofs = k0 + w * 8;
        #pragma unroll
        for (int t2 = 0; t2 < 2; ++t2)
            gl16(A + (size_t)(brow + t2 * 64 + lane) * K + kofs,
                 buf + w * 1024 + t2 * 512);
        #pragma unroll
        for (int t4 = 0; t4 < 4; ++t4)
            gl16(B + (size_t)(bcol + t4 * 64 + lane) * K + kofs,
                 buf + OFF_B + w * 2048 + t4 * 512);
    };

    f32x4 acc[8][4] = {};

    auto COMPUTE = [&](const ushort* rb) {
        bf16x8 af[8], bh[4];
        #pragma unroll
        for (int nt = 0; nt < 4; ++nt)
            bh[nt] = *(const bf16x8*)(rb + OFF_B + g * 2048 + (w * 64 + nt * 16 + lr) * 8);
        #pragma unroll
        for (int mt = 0; mt < 8; ++mt)
            af[mt] = *(const bf16x8*)(rb + g * 1024 + (mt * 16 + lr) * 8);
        #pragma unroll
        for (int mt = 0; mt < 8; ++mt)
            #pragma unroll
            for (int nt = 0; nt < 4; ++nt)
                acc[mt][nt] = __builtin_amdgcn_mfma_f32_16x16x32_bf16(bh[nt], af[mt], acc[mt][nt], 0, 0, 0);
    };

    STAGE(smem, 0);
    int cur = 0;
    for (int k0 = 32; k0 < K; k0 += 32) {
        STAGE(smem + (cur ^ 1) * SMEM_HALF, k0);
        asm volatile("s_waitcnt vmcnt(6)" ::: "memory");
        __builtin_amdgcn_sched_barrier(0);
        __builtin_amdgcn_s_barrier();
        COMPUTE(smem + cur * SMEM_HALF);
        __builtin_amdgcn_sched_barrier(0);
        __builtin_amdgcn_s_barrier();
        cur ^= 1;
    }
    asm volatile("s_waitcnt vmcnt(0)" ::: "memory");
    __builtin_amdgcn_sched_barrier(0);
    __builtin_amdgcn_s_barrier();
    COMPUTE(smem + cur * SMEM_HALF);

    #pragma unroll
    for (int mt = 0; mt < 8; ++mt) {
        const int gr = brow + mt * 16 + lr;
        if (gr >= M) continue;
        const float rs = (mode == 0) ? rscale[gr] : 0.0f;
        #pragma unroll
        for (int nt = 0; nt < 4; ++nt) {
            const int gc0 = bcol + w * 64 + nt * 16 + g * 4;
            float v0, v1, v2, v3;
            if (mode == 0) {
                v0 = acc[mt][nt][0] * rs; v1 = acc[mt][nt][1] * rs;
                v2 = acc[mt][nt][2] * rs; v3 = acc[mt][nt][3] * rs;
            } else {
                const float4 bv = *(const float4*)&bias[gc0];
                v0 = fmaxf(acc[mt][nt][0] + bv.x, 0.0f);
                v1 = fmaxf(acc[mt][nt][1] + bv.y, 0.0f);
                v2 = fmaxf(acc[mt][nt][2] + bv.z, 0.0f);
                v3 = fmaxf(acc[mt][nt][3] + bv.w, 0.0f);
            }
            uint2 pk;
            pk.x = (unsigned)f2bf(v0) | ((unsigned)f2bf(v1) << 16);
            pk.y = (unsigned)f2bf(v2) | ((unsigned)f2bf(v3) << 16);
            *(uint2*)(outp + (size_t)gr * ldc + gc0) = pk;
        }
    }
}

extern "C" void kernel_launch(void* const* d_in, const int* in_sizes, int n_in,
                              void* d_out, int out_size, void* d_ws, size_t ws_size,
                              hipStream_t stream) {
    const float* x  = (const float*)d_in[0];
    const void*  ei = d_in[1];
    const float* W1 = (const float*)d_in[2];
    const float* b1 = (const float*)d_in[3];
    const float* W2 = (const float*)d_in[4];
    const float* b2 = (const float*)d_in[5];
    float* out = (float*)d_out;

    const int N = N_NODES;
    const int E = in_sizes[1] / 2;
    const int MPAD = 50048;             // 391 * 128
    const int NSCB = (N + 511) / 512;   // 98 scan blocks

    // ---- workspace layout ----
    char* base = (char*)d_ws;
    int*   flag   = (int*)base;                        // 256 B slot
    int*   deg    = (int*)(base + 256);                // [51200]
    int*   rowptr = deg + 51200;
    int*   cur    = rowptr + 51200;
    float* dinv   = (float*)(cur + 51200);
    int*   bsum   = (int*)(dinv + 51200);              // [128]
    int*   adj    = bsum + 128;                        // [E]
    char*  p      = (char*)(adj + ((E + 63) & ~63));
    ushort* A1hi  = (ushort*)p;  p += (size_t)MPAD * 128 * 2;
    ushort* A1xx  = (ushort*)p;  p += (size_t)MPAD * 128 * 2;  // pad (tbuf tail)
    ushort* tbuf  = A1hi;        // [N][256] bf16, aliases A1hi+pad (dead after GEMM1)
    ushort* h1hi  = (ushort*)p;  p += (size_t)MPAD * 512 * 2;  // plain bf16
    ushort* Bt1   = (ushort*)p;  p += 512 * 128 * 2;
    ushort* Bt2   = (ushort*)p;  p += 256 * 512 * 2;
    ushort* xs    = (ushort*)p;  p += (size_t)MPAD * 128 * 2;  // bf16 dinv*x
    (void)A1xx;

    // 1. CSR build + normalization
    k_init<<<(N + 255) / 256, 256, 0, stream>>>(ei, flag, deg, N);
    k_hist<<<(E / 4 + 255) / 256, 256, 0, stream>>>(ei, flag, deg, E);
    k_scanA<<<NSCB, 512, 0, stream>>>(deg, rowptr + 1, bsum, N);
    k_scanC<<<NSCB, 512, 0, stream>>>(deg, rowptr, bsum, cur, dinv, N, NSCB);
    k_fill<<<((E + 255) / 256) * 8, 256, 0, stream>>>(ei, flag, cur, adj, E);

    // 2. weight prep (both) + pre-scaled features
    k_splitW<<<(512 * 128 + 256 * 512) / 256, 256, 0, stream>>>(W1, W2, Bt1, Bt2);
    k_scale<<<(N * 64 + 255) / 256, 256, 0, stream>>>(x, dinv, xs, N);

    // 3. layer-1 aggregation -> A1 (bf16)  [N,128]
    k_pull128b<<<(N + 3) / 4, 256, 0, stream>>>(rowptr, adj, dinv, xs, A1hi, N);

    // 4. h1 = relu(A1 @ W1 + b1) -> bf16 [N,512]   (2 col-blocks of 256)
    k_mfma<<<2 * 391, 256, 0, stream>>>(A1hi, Bt1, b1, nullptr, h1hi,
                                        N, 128, 512, 1, 2, 391);

    // 5. t = bf16( dinv[row] * (h1 @ W2) )  [N,256]  (1 col-block of 256)
    k_mfma<<<1 * 391, 256, 0, stream>>>(h1hi, Bt2, nullptr, dinv, tbuf,
                                        N, 512, 256, 0, 1, 391);

    // 6. layer-2 aggregation + bias + relu -> out  [N,250]
    k_pull250v<<<(N + 3) / 4, 256, 0, stream>>>(rowptr, adj, dinv, tbuf, b2, out, N);
}